// Round 1
// baseline (1772.007 us; speedup 1.0000x reference)
//
#include <hip/hip_runtime.h>
#include <hip/hip_bf16.h>

// Shapes (fixed by the problem)
#define SEQ 2048
#define DH  64
#define NH  16
#define DE  1024   // NH*DH

typedef float  f32x4  __attribute__((ext_vector_type(4)));
typedef float  fvec4  __attribute__((ext_vector_type(4)));
typedef __bf16 bf16x8 __attribute__((ext_vector_type(8)));

// ---------------------------------------------------------------------------
// GEMM: C[m,n] = sum_k A[m,k] * B[n,k]   (A·B^T), f32 in, bf16 MFMA compute.
// Store address: C[m*RS + (n>>6)*HS + (n&63)]
//   RS=64,  HS=SEQ*64 -> per-head [a][m][h] layout (QKV projections)
//   RS=DE,  HS=64     -> plain row-major [m][n]   (output projection)
// 256 thr = 4 waves; 64x64 tile; wave w owns rows [16w,16w+16), 4 col-tiles.
// gfx950 verified fragment layouts (guide §3):
//   A-frag: lane holds A[m=lane&15][k=(lane>>4)*8+j]
//   B-frag: lane holds B[n=lane&15][k=(lane>>4)*8+j]
//   C/D   : reg r -> row=(lane>>4)*4+r, col=lane&15
// ---------------------------------------------------------------------------
__global__ __launch_bounds__(256) void gemm_bt(
    const float* __restrict__ A, const float* __restrict__ B,
    float* __restrict__ C, int M, int N, int K, long RS, long HS)
{
    __shared__ __bf16 As[64][32];  // 4 KB
    __shared__ __bf16 Bs[64][32];  // 4 KB

    const int t    = threadIdx.x;
    const int wave = t >> 6;
    const int lane = t & 63;
    const int bm   = blockIdx.y * 64;
    const int bn   = blockIdx.x * 64;

    const int sr = t >> 2;          // staging: row t>>2, 8 floats at (t&3)*8
    const int sk = (t & 3) * 8;
    const float* Ap = A + (long)(bm + sr) * K + sk;
    const float* Bp = B + (long)(bn + sr) * K + sk;

    f32x4 acc0 = {0.f,0.f,0.f,0.f}, acc1 = {0.f,0.f,0.f,0.f};
    f32x4 acc2 = {0.f,0.f,0.f,0.f}, acc3 = {0.f,0.f,0.f,0.f};

    const int fr = lane & 15;
    const int kq = (lane >> 4) * 8;

    for (int k0 = 0; k0 < K; k0 += 32) {
        fvec4 a0 = *(const fvec4*)(Ap + k0);
        fvec4 a1 = *(const fvec4*)(Ap + k0 + 4);
        fvec4 b0 = *(const fvec4*)(Bp + k0);
        fvec4 b1 = *(const fvec4*)(Bp + k0 + 4);
        __syncthreads();  // prev iter's LDS reads done before overwrite
        bf16x8 av, bv;
        av[0]=(__bf16)a0.x; av[1]=(__bf16)a0.y; av[2]=(__bf16)a0.z; av[3]=(__bf16)a0.w;
        av[4]=(__bf16)a1.x; av[5]=(__bf16)a1.y; av[6]=(__bf16)a1.z; av[7]=(__bf16)a1.w;
        bv[0]=(__bf16)b0.x; bv[1]=(__bf16)b0.y; bv[2]=(__bf16)b0.z; bv[3]=(__bf16)b0.w;
        bv[4]=(__bf16)b1.x; bv[5]=(__bf16)b1.y; bv[6]=(__bf16)b1.z; bv[7]=(__bf16)b1.w;
        *(bf16x8*)&As[sr][sk] = av;   // one ds_write_b128 each
        *(bf16x8*)&Bs[sr][sk] = bv;
        __syncthreads();
        bf16x8 af  = *(const bf16x8*)&As[wave*16 + fr][kq];
        bf16x8 bf0 = *(const bf16x8*)&Bs[ 0 + fr][kq];
        bf16x8 bf1 = *(const bf16x8*)&Bs[16 + fr][kq];
        bf16x8 bf2 = *(const bf16x8*)&Bs[32 + fr][kq];
        bf16x8 bf3 = *(const bf16x8*)&Bs[48 + fr][kq];
        acc0 = __builtin_amdgcn_mfma_f32_16x16x32_bf16(af, bf0, acc0, 0, 0, 0);
        acc1 = __builtin_amdgcn_mfma_f32_16x16x32_bf16(af, bf1, acc1, 0, 0, 0);
        acc2 = __builtin_amdgcn_mfma_f32_16x16x32_bf16(af, bf2, acc2, 0, 0, 0);
        acc3 = __builtin_amdgcn_mfma_f32_16x16x32_bf16(af, bf3, acc3, 0, 0, 0);
    }

    const int m0 = bm + wave*16 + (lane >> 4) * 4;
    const int c0 = lane & 15;
    {
        int n = bn + 0*16 + c0; long nb = (long)(n >> 6) * HS + (n & 63);
        #pragma unroll
        for (int r = 0; r < 4; ++r) C[(long)(m0 + r) * RS + nb] = acc0[r];
    }
    {
        int n = bn + 1*16 + c0; long nb = (long)(n >> 6) * HS + (n & 63);
        #pragma unroll
        for (int r = 0; r < 4; ++r) C[(long)(m0 + r) * RS + nb] = acc1[r];
    }
    {
        int n = bn + 2*16 + c0; long nb = (long)(n >> 6) * HS + (n & 63);
        #pragma unroll
        for (int r = 0; r < 4; ++r) C[(long)(m0 + r) * RS + nb] = acc2[r];
    }
    {
        int n = bn + 3*16 + c0; long nb = (long)(n >> 6) * HS + (n & 63);
        #pragma unroll
        for (int r = 0; r < 4; ++r) C[(long)(m0 + r) * RS + nb] = acc3[r];
    }
}

// ---------------------------------------------------------------------------
// W_O [a][e][h] (16,1024,64) -> WoT [e][a*64+h]  (1024 x 1024 row-major)
// ---------------------------------------------------------------------------
__global__ __launch_bounds__(256) void transpose_wo(
    const float* __restrict__ WO, float* __restrict__ WoT)
{
    int i = blockIdx.x * 256 + threadIdx.x;     // over 16*1024*64 = 1M
    int h = i & 63;
    int e = (i >> 6) & 1023;
    int a = i >> 16;
    WoT[(long)e * DE + a * 64 + h] = WO[i];
}

// ---------------------------------------------------------------------------
// Reference semantics (Q/K roles swapped vs textbook attention):
//   s[c,C] = (k_c . q_C)/8 for C<=c ; p = softmax_C ; z[c,:] = sum_C p[C]*v_C
// One block per (head a, row c). Q/K/V layout [a][c][h]. Z: [c][a*64+h].
// ---------------------------------------------------------------------------
__global__ __launch_bounds__(256) void attn_kernel(
    const float* __restrict__ Q, const float* __restrict__ K,
    const float* __restrict__ V, float* __restrict__ Z)
{
    const int a = blockIdx.y;
    const int c = blockIdx.x;
    const int t = threadIdx.x;

    __shared__ alignas(16) float kv[DH];
    __shared__ float s[SEQ];          // 8 KB scores
    __shared__ float red[256];
    __shared__ float zp[4][DH];

    const float* kr = K + ((long)a * SEQ + c) * DH;
    if (t < DH) kv[t] = kr[t];
    __syncthreads();

    // phase 1: scores for C = t, t+256, ... <= c
    const float* qh = Q + (long)a * SEQ * DH;
    float lmax = -3.4e38f;
    for (int C = t; C <= c; C += 256) {
        const fvec4* qr = (const fvec4*)(qh + (long)C * DH);
        float acc = 0.f;
        #pragma unroll
        for (int j = 0; j < 16; ++j) {
            fvec4 qv = qr[j];
            fvec4 kk = ((const fvec4*)kv)[j];
            acc += qv.x*kk.x + qv.y*kk.y + qv.z*kk.z + qv.w*kk.w;
        }
        acc *= 0.125f;                 // 1/sqrt(DH)
        s[C] = acc;
        lmax = fmaxf(lmax, acc);
    }

    // phase 2: block max
    red[t] = lmax; __syncthreads();
    for (int st = 128; st > 0; st >>= 1) {
        if (t < st) red[t] = fmaxf(red[t], red[t + st]);
        __syncthreads();
    }
    float m = red[0];
    __syncthreads();                   // before red reuse

    // phase 3: exp + block sum
    float lsum = 0.f;
    for (int C = t; C <= c; C += 256) {
        float p = __expf(s[C] - m);
        s[C] = p;
        lsum += p;
    }
    red[t] = lsum; __syncthreads();    // also fences the s[] writes
    for (int st = 128; st > 0; st >>= 1) {
        if (t < st) red[t] += red[t + st];
        __syncthreads();
    }
    float inv = 1.0f / red[0];

    // phase 4: z[h] = sum_C p[C] * v[C][h]   (coalesced over h)
    const int h = t & 63, qtr = t >> 6;
    const float* vh = V + (long)a * SEQ * DH;
    float zacc = 0.f;
    for (int C = qtr; C <= c; C += 4)
        zacc += s[C] * vh[(long)C * DH + h];
    zp[qtr][h] = zacc;
    __syncthreads();
    if (t < DH) {
        float zres = (zp[0][t] + zp[1][t] + zp[2][t] + zp[3][t]) * inv;
        Z[(long)c * DE + a * 64 + t] = zres;
    }
}

// ---------------------------------------------------------------------------
extern "C" void kernel_launch(void* const* d_in, const int* in_sizes, int n_in,
                              void* d_out, int out_size, void* d_ws, size_t ws_size,
                              hipStream_t stream)
{
    const float* x  = (const float*)d_in[0];   // [1,2048,1024]
    const float* Wq = (const float*)d_in[1];   // [16,64,1024]
    const float* Wk = (const float*)d_in[2];
    const float* Wv = (const float*)d_in[3];
    const float* Wo = (const float*)d_in[4];   // [16,1024,64]
    float* out = (float*)d_out;                // [1,2048,1024]

    float* ws  = (float*)d_ws;                 // uses 37.75 MB of workspace
    float* q   = ws;                           // [a][c][h] 2M floats
    float* k   = q + (long)SEQ * DE;
    float* v   = k + (long)SEQ * DE;
    float* z   = v + (long)SEQ * DE;           // [c][a*64+h] 2M floats
    float* WoT = z + (long)SEQ * DE;           // [e][a*64+h] 1M floats

    transpose_wo<<<(NH * DE * DH) / 256, 256, 0, stream>>>(Wo, WoT);

    dim3 g(DE / 64, SEQ / 64);
    gemm_bt<<<g, 256, 0, stream>>>(x, Wq, q, SEQ, DE, DE, 64, (long)SEQ * 64);
    gemm_bt<<<g, 256, 0, stream>>>(x, Wk, k, SEQ, DE, DE, 64, (long)SEQ * 64);
    gemm_bt<<<g, 256, 0, stream>>>(x, Wv, v, SEQ, DE, DE, 64, (long)SEQ * 64);

    attn_kernel<<<dim3(SEQ, NH), 256, 0, stream>>>(q, k, v, z);

    gemm_bt<<<g, 256, 0, stream>>>(z, WoT, out, SEQ, DE, DE, DE, 64);
}

// Round 2
// 230.061 us; speedup vs baseline: 7.7023x; 7.7023x over previous
//
#include <hip/hip_runtime.h>
#include <hip/hip_bf16.h>

#define SEQ 2048
#define DH  64
#define NH  16
#define DE  1024   // NH*DH

typedef float  f32x4  __attribute__((ext_vector_type(4)));
typedef float  fvec4  __attribute__((ext_vector_type(4)));
typedef __bf16 bf16x8 __attribute__((ext_vector_type(8)));

#define MFMA16(A,B,C) __builtin_amdgcn_mfma_f32_16x16x32_bf16(A,B,C,0,0,0)

// ---------------------------------------------------------------------------
// gemm_qkv: C[m,n] = scale * sum_k A[m,k]*B[n,k], bf16 output with
// generalized store strides:  addr = m*RS + (n>>6)*HS + (n&63)*CS
//   q,k : RS=64, HS=SEQ*64, CS=1    -> [a][c][h] bf16
//   vt  : RS=1,  HS=64*SEQ, CS=SEQ  -> [a][h][c] bf16 (transposed V)
// 64x64 tile, 4 waves, verified gfx950 fragment layouts (guide §3).
// ---------------------------------------------------------------------------
__global__ __launch_bounds__(256) void gemm_qkv(
    const float* __restrict__ A, const float* __restrict__ B,
    __bf16* __restrict__ C, int K, long RS, long HS, long CS, float scale)
{
    __shared__ __bf16 As[64][32];
    __shared__ __bf16 Bs[64][32];

    const int t    = threadIdx.x;
    const int wave = t >> 6;
    const int lane = t & 63;
    const int bm   = blockIdx.y * 64;
    const int bn   = blockIdx.x * 64;

    const int sr = t >> 2;
    const int sk = (t & 3) * 8;
    const float* Ap = A + (long)(bm + sr) * K + sk;
    const float* Bp = B + (long)(bn + sr) * K + sk;

    f32x4 acc0 = {0.f,0.f,0.f,0.f}, acc1 = {0.f,0.f,0.f,0.f};
    f32x4 acc2 = {0.f,0.f,0.f,0.f}, acc3 = {0.f,0.f,0.f,0.f};

    const int fr = lane & 15;
    const int kq = (lane >> 4) * 8;

    for (int k0 = 0; k0 < K; k0 += 32) {
        fvec4 a0 = *(const fvec4*)(Ap + k0);
        fvec4 a1 = *(const fvec4*)(Ap + k0 + 4);
        fvec4 b0 = *(const fvec4*)(Bp + k0);
        fvec4 b1 = *(const fvec4*)(Bp + k0 + 4);
        __syncthreads();
        bf16x8 av, bv;
        av[0]=(__bf16)a0.x; av[1]=(__bf16)a0.y; av[2]=(__bf16)a0.z; av[3]=(__bf16)a0.w;
        av[4]=(__bf16)a1.x; av[5]=(__bf16)a1.y; av[6]=(__bf16)a1.z; av[7]=(__bf16)a1.w;
        bv[0]=(__bf16)b0.x; bv[1]=(__bf16)b0.y; bv[2]=(__bf16)b0.z; bv[3]=(__bf16)b0.w;
        bv[4]=(__bf16)b1.x; bv[5]=(__bf16)b1.y; bv[6]=(__bf16)b1.z; bv[7]=(__bf16)b1.w;
        *(bf16x8*)&As[sr][sk] = av;
        *(bf16x8*)&Bs[sr][sk] = bv;
        __syncthreads();
        bf16x8 af  = *(const bf16x8*)&As[wave*16 + fr][kq];
        bf16x8 bf0 = *(const bf16x8*)&Bs[ 0 + fr][kq];
        bf16x8 bf1 = *(const bf16x8*)&Bs[16 + fr][kq];
        bf16x8 bf2 = *(const bf16x8*)&Bs[32 + fr][kq];
        bf16x8 bf3 = *(const bf16x8*)&Bs[48 + fr][kq];
        acc0 = MFMA16(af, bf0, acc0);
        acc1 = MFMA16(af, bf1, acc1);
        acc2 = MFMA16(af, bf2, acc2);
        acc3 = MFMA16(af, bf3, acc3);
    }

    const int m0 = bm + wave*16 + (lane >> 4) * 4;
    const int c0 = lane & 15;
    f32x4 accs[4] = {acc0, acc1, acc2, acc3};
    #pragma unroll
    for (int nt = 0; nt < 4; ++nt) {
        int n = bn + nt*16 + c0;
        long nb = (long)(n >> 6) * HS + (long)(n & 63) * CS;
        #pragma unroll
        for (int r = 0; r < 4; ++r)
            C[(long)(m0 + r) * RS + nb] = (__bf16)(accs[nt][r] * scale);
    }
}

// ---------------------------------------------------------------------------
// f32-out GEMM for the output projection: C row-major [m][n] = A·B^T
// ---------------------------------------------------------------------------
__global__ __launch_bounds__(256) void gemm_bt(
    const float* __restrict__ A, const float* __restrict__ B,
    float* __restrict__ C, int K)
{
    __shared__ __bf16 As[64][32];
    __shared__ __bf16 Bs[64][32];

    const int t    = threadIdx.x;
    const int wave = t >> 6;
    const int lane = t & 63;
    const int bm   = blockIdx.y * 64;
    const int bn   = blockIdx.x * 64;

    const int sr = t >> 2;
    const int sk = (t & 3) * 8;
    const float* Ap = A + (long)(bm + sr) * K + sk;
    const float* Bp = B + (long)(bn + sr) * K + sk;

    f32x4 acc0 = {0.f,0.f,0.f,0.f}, acc1 = {0.f,0.f,0.f,0.f};
    f32x4 acc2 = {0.f,0.f,0.f,0.f}, acc3 = {0.f,0.f,0.f,0.f};

    const int fr = lane & 15;
    const int kq = (lane >> 4) * 8;

    for (int k0 = 0; k0 < K; k0 += 32) {
        fvec4 a0 = *(const fvec4*)(Ap + k0);
        fvec4 a1 = *(const fvec4*)(Ap + k0 + 4);
        fvec4 b0 = *(const fvec4*)(Bp + k0);
        fvec4 b1 = *(const fvec4*)(Bp + k0 + 4);
        __syncthreads();
        bf16x8 av, bv;
        av[0]=(__bf16)a0.x; av[1]=(__bf16)a0.y; av[2]=(__bf16)a0.z; av[3]=(__bf16)a0.w;
        av[4]=(__bf16)a1.x; av[5]=(__bf16)a1.y; av[6]=(__bf16)a1.z; av[7]=(__bf16)a1.w;
        bv[0]=(__bf16)b0.x; bv[1]=(__bf16)b0.y; bv[2]=(__bf16)b0.z; bv[3]=(__bf16)b0.w;
        bv[4]=(__bf16)b1.x; bv[5]=(__bf16)b1.y; bv[6]=(__bf16)b1.z; bv[7]=(__bf16)b1.w;
        *(bf16x8*)&As[sr][sk] = av;
        *(bf16x8*)&Bs[sr][sk] = bv;
        __syncthreads();
        bf16x8 af  = *(const bf16x8*)&As[wave*16 + fr][kq];
        bf16x8 bf0 = *(const bf16x8*)&Bs[ 0 + fr][kq];
        bf16x8 bf1 = *(const bf16x8*)&Bs[16 + fr][kq];
        bf16x8 bf2 = *(const bf16x8*)&Bs[32 + fr][kq];
        bf16x8 bf3 = *(const bf16x8*)&Bs[48 + fr][kq];
        acc0 = MFMA16(af, bf0, acc0);
        acc1 = MFMA16(af, bf1, acc1);
        acc2 = MFMA16(af, bf2, acc2);
        acc3 = MFMA16(af, bf3, acc3);
    }

    const int m0 = bm + wave*16 + (lane >> 4) * 4;
    const int c0 = lane & 15;
    f32x4 accs[4] = {acc0, acc1, acc2, acc3};
    #pragma unroll
    for (int nt = 0; nt < 4; ++nt) {
        int n = bn + nt*16 + c0;
        #pragma unroll
        for (int r = 0; r < 4; ++r)
            C[(long)(m0 + r) * DE + n] = accs[nt][r];
    }
}

// ---------------------------------------------------------------------------
// W_O [a][e][h] -> WoT [e][a*64+h]
// ---------------------------------------------------------------------------
__global__ __launch_bounds__(256) void transpose_wo(
    const float* __restrict__ WO, float* __restrict__ WoT)
{
    int i = blockIdx.x * 256 + threadIdx.x;
    int h = i & 63;
    int e = (i >> 6) & 1023;
    int a = i >> 16;
    WoT[(long)e * DE + a * 64 + h] = WO[i];
}

// ---------------------------------------------------------------------------
// MFMA flash attention (reference roles: s[c,C] = k_c·q_C/8, C<=c).
// Grid (16, NH), 512 thr = 8 waves. Waves 0-3 handle c-tile bx, waves 4-7
// handle c-tile 31-bx (causal load balance: every SIMD gets 33 tile-steps).
// Per wave: rows = tile*64 + wsub*16. K pre-scaled by 0.125 in projection.
// No max-subtraction softmax: |s| <= |k||q|/8 ~ 8 -> exp safe in f32.
// Row-sum via MFMA with all-ones B (lands in C/D layout = O layout).
// P C/D->A-frag via per-wave XOR-swizzled LDS (no __syncthreads anywhere).
// ---------------------------------------------------------------------------
__global__ __launch_bounds__(512) void attn_mfma(
    const __bf16* __restrict__ Qb, const __bf16* __restrict__ Kb,
    const __bf16* __restrict__ Vtb, float* __restrict__ Z)
{
    __shared__ __bf16 Plds[8][16][64];   // 16 KB, per-wave private

    const int a    = blockIdx.y;
    const int t    = threadIdx.x;
    const int wave = t >> 6;
    const int lane = t & 63;
    const int half = wave >> 2;
    const int wsub = wave & 3;
    const int jt   = half ? (31 - (int)blockIdx.x) : (int)blockIdx.x;
    const int c0   = jt * 64;
    const int il   = lane & 15;
    const int q4   = lane >> 4;

    // K A-fragments: fixed rows for this wave, both k-chunks
    const __bf16* kp = Kb + ((long)a*SEQ + c0 + wsub*16 + il)*DH + q4*8;
    bf16x8 af0 = *(const bf16x8*)(kp);
    bf16x8 af1 = *(const bf16x8*)(kp + 32);

    bf16x8 ones;
    #pragma unroll
    for (int j = 0; j < 8; ++j) ones[j] = (__bf16)1.0f;

    f32x4 o[4];
    #pragma unroll
    for (int ht = 0; ht < 4; ++ht) o[ht] = (f32x4){0.f,0.f,0.f,0.f};
    f32x4 lacc = {0.f,0.f,0.f,0.f};

    const __bf16* qbase = Qb + ((long)a*SEQ + il)*DH + q4*8;
    const __bf16* vbase = Vtb + ((long)a*DH + il)*SEQ + q4*8;

    for (int n0 = 0; n0 <= c0; n0 += 64) {
        // ---- S = K·Q^T for this 64-col tile
        const __bf16* qp = qbase + (long)n0 * DH;
        f32x4 sa[4];
        #pragma unroll
        for (int nt = 0; nt < 4; ++nt) {
            sa[nt] = (f32x4){0.f,0.f,0.f,0.f};
            bf16x8 b0 = *(const bf16x8*)(qp + (long)nt*16*DH);
            bf16x8 b1 = *(const bf16x8*)(qp + (long)nt*16*DH + 32);
            sa[nt] = MFMA16(af0, b0, sa[nt]);
            sa[nt] = MFMA16(af1, b1, sa[nt]);
        }
        // ---- causal mask on the diagonal tile
        if (n0 == c0) {
            #pragma unroll
            for (int nt = 0; nt < 4; ++nt) {
                int col = nt*16 + il;
                #pragma unroll
                for (int r = 0; r < 4; ++r) {
                    int row = wsub*16 + q4*4 + r;
                    if (col > row) sa[nt][r] = -1e30f;
                }
            }
        }
        // ---- P = exp(S), C/D layout -> LDS (XOR swizzle on 16B blocks)
        #pragma unroll
        for (int nt = 0; nt < 4; ++nt) {
            #pragma unroll
            for (int r = 0; r < 4; ++r) {
                float p = __expf(sa[nt][r]);
                int row = q4*4 + r;
                int col = nt*16 + il;
                int cs  = ((((col >> 3) ^ row) & 7) << 3) | (col & 7);
                Plds[wave][row][cs] = (__bf16)p;
            }
        }
        // ---- read P back in A-fragment layout
        bf16x8 pf0 = *(const bf16x8*)&Plds[wave][il][(((0 + q4) ^ il) & 7) << 3];
        bf16x8 pf1 = *(const bf16x8*)&Plds[wave][il][(((4 + q4) ^ il) & 7) << 3];
        // ---- row sums via MFMA with ones (same C/D layout as O)
        lacc = MFMA16(pf0, ones, lacc);
        lacc = MFMA16(pf1, ones, lacc);
        // ---- O += P · V   (B from transposed V)
        const __bf16* vp = vbase + n0;
        #pragma unroll
        for (int ht = 0; ht < 4; ++ht) {
            bf16x8 v0 = *(const bf16x8*)(vp + (long)ht*16*SEQ);
            bf16x8 v1 = *(const bf16x8*)(vp + (long)ht*16*SEQ + 32);
            o[ht] = MFMA16(pf0, v0, o[ht]);
            o[ht] = MFMA16(pf1, v1, o[ht]);
        }
    }

    float inv[4];
    #pragma unroll
    for (int r = 0; r < 4; ++r) inv[r] = 1.0f / lacc[r];

    #pragma unroll
    for (int ht = 0; ht < 4; ++ht) {
        #pragma unroll
        for (int r = 0; r < 4; ++r) {
            long row = c0 + wsub*16 + q4*4 + r;
            Z[row * DE + a*64 + ht*16 + il] = o[ht][r] * inv[r];
        }
    }
}

// ---------------------------------------------------------------------------
extern "C" void kernel_launch(void* const* d_in, const int* in_sizes, int n_in,
                              void* d_out, int out_size, void* d_ws, size_t ws_size,
                              hipStream_t stream)
{
    const float* x  = (const float*)d_in[0];   // [1,2048,1024]
    const float* Wq = (const float*)d_in[1];   // [16,64,1024]
    const float* Wk = (const float*)d_in[2];
    const float* Wv = (const float*)d_in[3];
    const float* Wo = (const float*)d_in[4];   // [16,1024,64]
    float* out = (float*)d_out;

    const long NE = (long)SEQ * DE;            // 2M elements
    __bf16* wsb = (__bf16*)d_ws;
    __bf16* qb  = wsb;                         // [a][c][h] bf16, 4 MB
    __bf16* kb  = wsb + NE;                    // [a][c][h] bf16 (pre-scaled)
    __bf16* vtb = wsb + 2*NE;                  // [a][h][c] bf16
    float*  z   = (float*)(wsb + 3*NE);        // [c][a*64+h] f32, 8 MB
    float*  WoT = z + NE;                      // [e][a*64+h] f32, 4 MB

    transpose_wo<<<(NH * DE * DH) / 256, 256, 0, stream>>>(Wo, WoT);

    dim3 g(DE / 64, SEQ / 64);
    gemm_qkv<<<g, 256, 0, stream>>>(x, Wq, qb,  DE, 64, (long)SEQ*64, 1,   1.0f);
    gemm_qkv<<<g, 256, 0, stream>>>(x, Wk, kb,  DE, 64, (long)SEQ*64, 1,   0.125f);
    gemm_qkv<<<g, 256, 0, stream>>>(x, Wv, vtb, DE, 1, (long)DH*SEQ, SEQ, 1.0f);

    attn_mfma<<<dim3(16, NH), 512, 0, stream>>>(qb, kb, vtb, z);

    gemm_bt<<<g, 256, 0, stream>>>(z, WoT, out, DE);
}

// Round 3
// 209.961 us; speedup vs baseline: 8.4397x; 1.0957x over previous
//
#include <hip/hip_runtime.h>
#include <hip/hip_bf16.h>

#define SEQ 2048
#define DH  64
#define NH  16
#define DE  1024   // NH*DH

typedef float  f32x4  __attribute__((ext_vector_type(4)));
typedef float  fvec4  __attribute__((ext_vector_type(4)));
typedef __bf16 bf16x8 __attribute__((ext_vector_type(8)));

#define MFMA16(A,B,C) __builtin_amdgcn_mfma_f32_16x16x32_bf16(A,B,C,0,0,0)

// async 16B global -> LDS (direct, no VGPR round trip)
__device__ __forceinline__ void gll16(void* lds, const void* g) {
    __builtin_amdgcn_global_load_lds(
        (const __attribute__((address_space(1))) unsigned int*)g,
        (__attribute__((address_space(3))) unsigned int*)lds, 16, 0, 0);
}

// ---------------------------------------------------------------------------
// One-shot f32 -> bf16 prep: xb, wqb, wkb(*0.125), wvb, wotb(transposed WO).
// 6M elements, 8 per thread, all regions 8-aligned so stores are 16B.
// ---------------------------------------------------------------------------
__global__ __launch_bounds__(256) void conv_all(
    const float* __restrict__ x,  const float* __restrict__ Wq,
    const float* __restrict__ Wk, const float* __restrict__ Wv,
    const float* __restrict__ Wo, __bf16* __restrict__ xb,
    __bf16* __restrict__ wqb, __bf16* __restrict__ wkb,
    __bf16* __restrict__ wvb, __bf16* __restrict__ wotb)
{
    long i = ((long)blockIdx.x * 256 + threadIdx.x) * 8;
    const float* src; __bf16* dst; float sc = 1.0f; long j;
    if (i < 2097152)      { j = i;            src = x  + j; dst = xb  + j; }
    else if (i < 3145728) { j = i - 2097152;  src = Wq + j; dst = wqb + j; }
    else if (i < 4194304) { j = i - 3145728;  src = Wk + j; dst = wkb + j; sc = 0.125f; }
    else if (i < 5242880) { j = i - 4194304;  src = Wv + j; dst = wvb + j; }
    else                  { j = i - 5242880;  src = Wo + j;
                            long a = j >> 16, e = (j >> 6) & 1023, h = j & 63;
                            dst = wotb + e * DE + a * 64 + h; }
    fvec4 u = *(const fvec4*)src;
    fvec4 w = *(const fvec4*)(src + 4);
    bf16x8 o;
    o[0]=(__bf16)(u.x*sc); o[1]=(__bf16)(u.y*sc); o[2]=(__bf16)(u.z*sc); o[3]=(__bf16)(u.w*sc);
    o[4]=(__bf16)(w.x*sc); o[5]=(__bf16)(w.y*sc); o[6]=(__bf16)(w.z*sc); o[7]=(__bf16)(w.w*sc);
    *(bf16x8*)dst = o;
}

// ---------------------------------------------------------------------------
// QKV projection GEMM, m97-style: bf16 in, global_load_lds(16B) staging,
// BM=64 BN=128 BK=32, 256 thr = 4 waves, wave tile 32x64 (2x4 16-tiles).
// blockIdx.z selects {q,k,v}. Store addr = m*RS + (n>>6)*131072 + (n&63)*NS:
//   q,k: RS=64, NS=1   -> [a][c][h]      (K already pre-scaled by 0.125)
//   v  : RS=1,  NS=SEQ -> [a][h][c]      (transposed V)
// ---------------------------------------------------------------------------
__global__ __launch_bounds__(256) void gemm_qkv64(
    const __bf16* __restrict__ Ab, const __bf16* __restrict__ Bq,
    const __bf16* __restrict__ Bk, const __bf16* __restrict__ Bv,
    __bf16* __restrict__ Cq, __bf16* __restrict__ Ck, __bf16* __restrict__ Cv)
{
    __shared__ __bf16 As[64][32];    // 4 KB
    __shared__ __bf16 Bs[128][32];   // 8 KB

    const int zi = blockIdx.z;
    const __bf16* B = (zi == 0) ? Bq : ((zi == 1) ? Bk : Bv);
    __bf16* C       = (zi == 0) ? Cq : ((zi == 1) ? Ck : Cv);
    const long RS = (zi == 2) ? 1 : 64;
    const long NS = (zi == 2) ? SEQ : 1;

    const int t = threadIdx.x, wave = t >> 6, lane = t & 63;
    const int bm = blockIdx.y * 64, bn = blockIdx.x * 128;
    const int r0 = t >> 2, kp = t & 3;

    const __bf16* Ag  = Ab + (long)(bm + r0) * DE + kp * 8;
    const __bf16* Bg0 = B  + (long)(bn + r0) * DE + kp * 8;
    const __bf16* Bg1 = B  + (long)(bn + 64 + r0) * DE + kp * 8;
    __bf16* Al  = &As[r0][kp * 8];        // lds = t*16B (wave-uniform + lane*16)
    __bf16* Bl0 = &Bs[r0][kp * 8];
    __bf16* Bl1 = &Bs[64 + r0][kp * 8];

    f32x4 acc[2][4];
    #pragma unroll
    for (int i = 0; i < 2; ++i)
        #pragma unroll
        for (int j = 0; j < 4; ++j) acc[i][j] = (f32x4){0.f,0.f,0.f,0.f};

    const int il = lane & 15, q4 = lane >> 4;
    const int wr = (wave & 1) * 32, wc = (wave >> 1) * 64;

    for (int k0 = 0; k0 < DE; k0 += 32) {
        __syncthreads();                       // prev ds_reads done
        gll16(Al,  Ag  + k0);
        gll16(Bl0, Bg0 + k0);
        gll16(Bl1, Bg1 + k0);
        __syncthreads();                       // staging drained (vmcnt(0))
        bf16x8 af[2], bff[4];
        #pragma unroll
        for (int mt = 0; mt < 2; ++mt) af[mt]  = *(const bf16x8*)&As[wr + mt*16 + il][q4*8];
        #pragma unroll
        for (int nt = 0; nt < 4; ++nt) bff[nt] = *(const bf16x8*)&Bs[wc + nt*16 + il][q4*8];
        #pragma unroll
        for (int mt = 0; mt < 2; ++mt)
            #pragma unroll
            for (int nt = 0; nt < 4; ++nt)
                acc[mt][nt] = MFMA16(af[mt], bff[nt], acc[mt][nt]);
    }

    #pragma unroll
    for (int mt = 0; mt < 2; ++mt) {
        const int m0 = bm + wr + mt*16 + q4*4;
        #pragma unroll
        for (int nt = 0; nt < 4; ++nt) {
            int n = bn + wc + nt*16 + il;
            long nb = (long)(n >> 6) * 131072 + (long)(n & 63) * NS;
            #pragma unroll
            for (int r = 0; r < 4; ++r)
                C[(long)(m0 + r) * RS + nb] = (__bf16)acc[mt][nt][r];
        }
    }
}

// ---------------------------------------------------------------------------
// Output projection: out[m][n] = sum_k Z[m][k] * WoT[n][k], f32 out row-major.
// Same m97-style structure, BM=64 BN=128 -> grid (8,32) = 256 blocks.
// ---------------------------------------------------------------------------
__global__ __launch_bounds__(256) void gemm_out64(
    const __bf16* __restrict__ Ab, const __bf16* __restrict__ B,
    float* __restrict__ C)
{
    __shared__ __bf16 As[64][32];
    __shared__ __bf16 Bs[128][32];

    const int t = threadIdx.x, wave = t >> 6, lane = t & 63;
    const int bm = blockIdx.y * 64, bn = blockIdx.x * 128;
    const int r0 = t >> 2, kp = t & 3;

    const __bf16* Ag  = Ab + (long)(bm + r0) * DE + kp * 8;
    const __bf16* Bg0 = B  + (long)(bn + r0) * DE + kp * 8;
    const __bf16* Bg1 = B  + (long)(bn + 64 + r0) * DE + kp * 8;
    __bf16* Al  = &As[r0][kp * 8];
    __bf16* Bl0 = &Bs[r0][kp * 8];
    __bf16* Bl1 = &Bs[64 + r0][kp * 8];

    f32x4 acc[2][4];
    #pragma unroll
    for (int i = 0; i < 2; ++i)
        #pragma unroll
        for (int j = 0; j < 4; ++j) acc[i][j] = (f32x4){0.f,0.f,0.f,0.f};

    const int il = lane & 15, q4 = lane >> 4;
    const int wr = (wave & 1) * 32, wc = (wave >> 1) * 64;

    for (int k0 = 0; k0 < DE; k0 += 32) {
        __syncthreads();
        gll16(Al,  Ag  + k0);
        gll16(Bl0, Bg0 + k0);
        gll16(Bl1, Bg1 + k0);
        __syncthreads();
        bf16x8 af[2], bff[4];
        #pragma unroll
        for (int mt = 0; mt < 2; ++mt) af[mt]  = *(const bf16x8*)&As[wr + mt*16 + il][q4*8];
        #pragma unroll
        for (int nt = 0; nt < 4; ++nt) bff[nt] = *(const bf16x8*)&Bs[wc + nt*16 + il][q4*8];
        #pragma unroll
        for (int mt = 0; mt < 2; ++mt)
            #pragma unroll
            for (int nt = 0; nt < 4; ++nt)
                acc[mt][nt] = MFMA16(af[mt], bff[nt], acc[mt][nt]);
    }

    #pragma unroll
    for (int mt = 0; mt < 2; ++mt) {
        const int m0 = bm + wr + mt*16 + q4*4;
        #pragma unroll
        for (int nt = 0; nt < 4; ++nt) {
            int n = bn + wc + nt*16 + il;
            #pragma unroll
            for (int r = 0; r < 4; ++r)
                C[(long)(m0 + r) * DE + n] = acc[mt][nt][r];
        }
    }
}

// ---------------------------------------------------------------------------
// Split-C MFMA flash attention (reference roles: s[c,C]=k_c.q_C/8, C<=c).
// Grid (NH, 32): a = bx, jt = 31 - by (big tiles dispatched first).
// 512 thr = 8 waves; wsub = wave&3 picks the 16-row strip of c-tile jt;
// half = wave>>2 picks which half of the C-range [0, jt] of 64-col tiles.
// No max-subtraction softmax (|s| <~ 8 sigma -> exp safe in f32), so partial
// (O, l) from the two halves combine by plain addition through LDS.
// P goes C/D-layout -> A-frag-layout via per-wave XOR-swizzled LDS.
// Row-sum l via MFMA with all-ones B (lands in C/D layout == O layout).
// Z written as bf16 [c][a*64+h] for the bf16 output-projection GEMM.
// ---------------------------------------------------------------------------
struct AttnSM {
    union {
        __bf16 P[8][16][64];                       // 16 KB, per-wave private
        struct { float O[4][64][16]; float l[4][64][4]; } cb;  // 20 KB combine
    };
};

__global__ __launch_bounds__(512, 4) void attn_mfma(
    const __bf16* __restrict__ Qb, const __bf16* __restrict__ Kb,
    const __bf16* __restrict__ Vtb, __bf16* __restrict__ Z)
{
    __shared__ AttnSM sm;

    const int a    = blockIdx.x;
    const int jt   = 31 - (int)blockIdx.y;
    const int t    = threadIdx.x;
    const int wave = t >> 6;
    const int lane = t & 63;
    const int half = wave >> 2;
    const int wsub = wave & 3;
    const int c0   = jt * 64;
    const int il   = lane & 15;
    const int q4   = lane >> 4;

    const int h0   = (jt + 2) >> 1;            // ceil((jt+1)/2) tiles in half 0
    const int nbeg = half ? h0 * 64 : 0;
    const int nend = half ? c0 : (h0 - 1) * 64;

    // K A-fragments: fixed rows for this wave
    const __bf16* kp = Kb + ((long)a*SEQ + c0 + wsub*16 + il)*DH + q4*8;
    bf16x8 af0 = *(const bf16x8*)(kp);
    bf16x8 af1 = *(const bf16x8*)(kp + 32);

    bf16x8 ones;
    #pragma unroll
    for (int j = 0; j < 8; ++j) ones[j] = (__bf16)1.0f;

    f32x4 o[4];
    #pragma unroll
    for (int ht = 0; ht < 4; ++ht) o[ht] = (f32x4){0.f,0.f,0.f,0.f};
    f32x4 lacc = {0.f,0.f,0.f,0.f};

    const __bf16* qbase = Qb  + ((long)a*SEQ + il)*DH + q4*8;
    const __bf16* vbase = Vtb + ((long)a*DH + il)*SEQ + q4*8;

    for (int n0 = nbeg; n0 <= nend; n0 += 64) {
        const __bf16* qp = qbase + (long)n0 * DH;
        const __bf16* vp = vbase + n0;
        // hoist V-frag loads: vmcnt covers the exp/LDS chain below
        bf16x8 vv0[4], vv1[4];
        #pragma unroll
        for (int ht = 0; ht < 4; ++ht) {
            vv0[ht] = *(const bf16x8*)(vp + (long)ht*16*SEQ);
            vv1[ht] = *(const bf16x8*)(vp + (long)ht*16*SEQ + 32);
        }
        // ---- S = K.Q^T
        f32x4 sa[4];
        #pragma unroll
        for (int nt = 0; nt < 4; ++nt) {
            sa[nt] = (f32x4){0.f,0.f,0.f,0.f};
            bf16x8 b0 = *(const bf16x8*)(qp + (long)nt*16*DH);
            bf16x8 b1 = *(const bf16x8*)(qp + (long)nt*16*DH + 32);
            sa[nt] = MFMA16(af0, b0, sa[nt]);
            sa[nt] = MFMA16(af1, b1, sa[nt]);
        }
        // ---- causal mask (diagonal tile only)
        if (n0 == c0) {
            #pragma unroll
            for (int nt = 0; nt < 4; ++nt) {
                int col = nt*16 + il;
                #pragma unroll
                for (int r = 0; r < 4; ++r) {
                    int row = wsub*16 + q4*4 + r;
                    if (col > row) sa[nt][r] = -1e30f;
                }
            }
        }
        // ---- P = exp(S) -> LDS (XOR swizzle on 16B blocks)
        #pragma unroll
        for (int nt = 0; nt < 4; ++nt) {
            #pragma unroll
            for (int r = 0; r < 4; ++r) {
                float p = __expf(sa[nt][r]);
                int row = q4*4 + r;
                int col = nt*16 + il;
                int cs  = ((((col >> 3) ^ row) & 7) << 3) | (col & 7);
                sm.P[wave][row][cs] = (__bf16)p;
            }
        }
        // ---- P back in A-fragment layout
        bf16x8 pf0 = *(const bf16x8*)&sm.P[wave][il][(((0 + q4) ^ il) & 7) << 3];
        bf16x8 pf1 = *(const bf16x8*)&sm.P[wave][il][(((4 + q4) ^ il) & 7) << 3];
        // ---- l += rowsum(P), O += P.V
        lacc = MFMA16(pf0, ones, lacc);
        lacc = MFMA16(pf1, ones, lacc);
        #pragma unroll
        for (int ht = 0; ht < 4; ++ht) {
            o[ht] = MFMA16(pf0, vv0[ht], o[ht]);
            o[ht] = MFMA16(pf1, vv1[ht], o[ht]);
        }
    }

    // ---- combine halves through LDS (P buffer re-used; fence first)
    __syncthreads();
    if (half) {
        #pragma unroll
        for (int ht = 0; ht < 4; ++ht)
            *(f32x4*)&sm.cb.O[wsub][lane][ht*4] = o[ht];
        *(f32x4*)&sm.cb.l[wsub][lane][0] = lacc;
    }
    __syncthreads();
    if (!half) {
        #pragma unroll
        for (int ht = 0; ht < 4; ++ht) {
            f32x4 p = *(const f32x4*)&sm.cb.O[wsub][lane][ht*4];
            o[ht] += p;
        }
        lacc += *(const f32x4*)&sm.cb.l[wsub][lane][0];
        float inv[4];
        #pragma unroll
        for (int r = 0; r < 4; ++r) inv[r] = 1.0f / lacc[r];
        #pragma unroll
        for (int ht = 0; ht < 4; ++ht)
            #pragma unroll
            for (int r = 0; r < 4; ++r) {
                long row = c0 + wsub*16 + q4*4 + r;
                Z[row * DE + a*64 + ht*16 + il] = (__bf16)(o[ht][r] * inv[r]);
            }
    }
}

// ---------------------------------------------------------------------------
extern "C" void kernel_launch(void* const* d_in, const int* in_sizes, int n_in,
                              void* d_out, int out_size, void* d_ws, size_t ws_size,
                              hipStream_t stream)
{
    const float* x  = (const float*)d_in[0];
    const float* Wq = (const float*)d_in[1];
    const float* Wk = (const float*)d_in[2];
    const float* Wv = (const float*)d_in[3];
    const float* Wo = (const float*)d_in[4];
    float* out = (float*)d_out;

    const long M1 = 1024 * 1024;
    __bf16* wsb  = (__bf16*)d_ws;              // 14M bf16 = 28 MB
    __bf16* xb   = wsb;                        // [c][e]      2M
    __bf16* wqb  = wsb + 2*M1;                 // [a*64+h][e] 1M
    __bf16* wkb  = wsb + 3*M1;                 // (pre-scaled 0.125)
    __bf16* wvb  = wsb + 4*M1;
    __bf16* wotb = wsb + 5*M1;                 // [e][a*64+h] 1M
    __bf16* qb   = wsb + 6*M1;                 // [a][c][h]   2M
    __bf16* kb   = wsb + 8*M1;                 // [a][c][h]
    __bf16* vtb  = wsb + 10*M1;                // [a][h][c]
    __bf16* zb   = wsb + 12*M1;                // [c][a*64+h]

    conv_all<<<3072, 256, 0, stream>>>(x, Wq, Wk, Wv, Wo,
                                       xb, wqb, wkb, wvb, wotb);

    gemm_qkv64<<<dim3(8, 32, 3), 256, 0, stream>>>(xb, wqb, wkb, wvb,
                                                   qb, kb, vtb);

    attn_mfma<<<dim3(NH, 32), 512, 0, stream>>>(qb, kb, vtb, zb);

    gemm_out64<<<dim3(8, 32), 256, 0, stream>>>(zb, wotb, out);
}